// Round 1
// baseline (300.123 us; speedup 1.0000x reference)
//
#include <hip/hip_runtime.h>
#include <math.h>

// NAMClassifier: B=16384 rows, F=256 independent 1->64->32->1 MLPs.
// Phase 1: each thread computes sum over its 16-feature group for one row.
// Phase 2: reduce 16 partials per row, add bias, sigmoid.

#define NAM_B  16384
#define NAM_F  256
#define NAM_H1 64
#define NAM_H2 32
#define FPG    16            // features per group
#define NG     (NAM_F / FPG) // 16 groups
#define BT     256           // rows per block (== blockDim.x)

__global__ __launch_bounds__(256) void nam_phase1(
    const float* __restrict__ x,    // [B, F]
    const float* __restrict__ W1,   // [F, 1, H1]
    const float* __restrict__ b1,   // [F, H1]
    const float* __restrict__ W2,   // [F, H1, H2]
    const float* __restrict__ b2,   // [F, H2]
    const float* __restrict__ W3,   // [F, H2, 1]
    const float* __restrict__ b3,   // [F, 1]
    float* __restrict__ partial)    // [NG, B]
{
    const int tile = blockIdx.x % (NAM_B / BT);   // 64 row tiles
    const int g    = blockIdx.x / (NAM_B / BT);   // 16 feature groups
    const int brow = tile * BT + threadIdx.x;
    const int f0   = g * FPG;

    // This thread's x chunk: 16 consecutive floats == one aligned 64B line.
    float xr[FPG];
    const float* xp = x + (size_t)brow * NAM_F + f0;
    #pragma unroll
    for (int j = 0; j < FPG / 4; ++j) {
        const float4 v = *reinterpret_cast<const float4*>(xp + 4 * j);
        xr[4*j+0] = v.x; xr[4*j+1] = v.y; xr[4*j+2] = v.z; xr[4*j+3] = v.w;
    }

    float psum = 0.0f;
    for (int ff = 0; ff < FPG; ++ff) {
        const int f = f0 + ff;
        const float xv = xr[ff];
        const float* __restrict__ W1f = W1 + f * NAM_H1;
        const float* __restrict__ b1f = b1 + f * NAM_H1;
        const float* __restrict__ W2f = W2 + (size_t)f * NAM_H1 * NAM_H2;
        const float* __restrict__ b2f = b2 + f * NAM_H2;
        const float* __restrict__ W3f = W3 + f * NAM_H2;

        float acc[NAM_H2];
        #pragma unroll
        for (int k = 0; k < NAM_H2; ++k) acc[k] = b2f[k];

        // h-outer / k-inner: live state is just acc[32] + a few scalars.
        // All weight reads are block-uniform -> expect s_load + v_fmac v,s,v.
        #pragma unroll 4
        for (int h = 0; h < NAM_H1; ++h) {
            const float h1v = fmaxf(fmaf(xv, W1f[h], b1f[h]), 0.0f);
            #pragma unroll
            for (int k = 0; k < NAM_H2; ++k)
                acc[k] = fmaf(h1v, W2f[h * NAM_H2 + k], acc[k]);
        }

        float c = b3[f];
        #pragma unroll
        for (int k = 0; k < NAM_H2; ++k)
            c = fmaf(fmaxf(acc[k], 0.0f), W3f[k], c);
        psum += c;
    }

    partial[(size_t)g * NAM_B + brow] = psum;
}

__global__ __launch_bounds__(256) void nam_phase2(
    const float* __restrict__ partial,  // [NG, B]
    const float* __restrict__ bias,     // [1]
    float* __restrict__ out)            // [2*B]: logits then probs
{
    const int b = blockIdx.x * blockDim.x + threadIdx.x;
    float s = bias[0];
    #pragma unroll
    for (int g = 0; g < NG; ++g) s += partial[(size_t)g * NAM_B + b];
    out[b] = s;                                   // logits
    out[NAM_B + b] = 1.0f / (1.0f + expf(-s));    // probs
}

extern "C" void kernel_launch(void* const* d_in, const int* in_sizes, int n_in,
                              void* d_out, int out_size, void* d_ws, size_t ws_size,
                              hipStream_t stream) {
    const float* x    = (const float*)d_in[0];
    const float* W1   = (const float*)d_in[1];
    const float* b1   = (const float*)d_in[2];
    const float* W2   = (const float*)d_in[3];
    const float* b2   = (const float*)d_in[4];
    const float* W3   = (const float*)d_in[5];
    const float* b3   = (const float*)d_in[6];
    const float* bias = (const float*)d_in[7];
    float* out     = (float*)d_out;
    float* partial = (float*)d_ws;  // NG*B floats = 1 MiB, fully overwritten

    nam_phase1<<<dim3(NG * (NAM_B / BT)), BT, 0, stream>>>(
        x, W1, b1, W2, b2, W3, b3, partial);
    nam_phase2<<<dim3(NAM_B / BT), BT, 0, stream>>>(partial, bias, out);
}

// Round 2
// 134.596 us; speedup vs baseline: 2.2298x; 2.2298x over previous
//
#include <hip/hip_runtime.h>
#include <hip/hip_bf16.h>
#include <math.h>

// NAMClassifier: B=16384 rows, F=256 independent 1->64->32->1 MLPs.
// MFMA version: layer2 (17.2 of 18.4 GFLOP) via mfma_f32_16x16x32_bf16.
// Block = 512 thr (8 waves x 16 rows), 16 features per block (8 pairs staged).

#define NAM_B  16384
#define NAM_F  256
#define NAM_H1 64
#define NAM_H2 32
#define RPB    128              // rows per block
#define FPB    16               // features per block group
#define NG     (NAM_F / FPB)    // 16
#define NT     (NAM_B / RPB)    // 128

typedef __attribute__((ext_vector_type(8))) short short8_t;
typedef __attribute__((ext_vector_type(4))) float float4_t;

__device__ __forceinline__ short f2bf(float f) {
    union { __hip_bfloat16 h; short s; } u;
    u.h = __float2bfloat16(f);   // RNE
    return u.s;
}

__global__ __launch_bounds__(512) void nam_mfma(
    const float* __restrict__ x,    // [B, F]
    const float* __restrict__ W1,   // [F, 64]
    const float* __restrict__ b1,   // [F, 64]
    const float* __restrict__ W2,   // [F, 64, 32]
    const float* __restrict__ b2,   // [F, 32]
    const float* __restrict__ W3,   // [F, 32]
    const float* __restrict__ b3,   // [F]
    float* __restrict__ partial)    // [NG, B]
{
    // LDS
    __shared__ float xs[RPB][17];            // x tile, pad 17 (conflict-free col reads)
    __shared__ short w2s[2][8][33][8];       // bf16 W2, [kblk a][n pad33][j] per feature q
    __shared__ float w1s[2][NAM_H1], b1s[2][NAM_H1];
    __shared__ float b2s[2][NAM_H2], w3s[2][NAM_H2];

    const int t    = threadIdx.x;
    const int tile = blockIdx.x % NT;
    const int g    = blockIdx.x / NT;
    const int rbase = tile * RPB;
    const int f0    = g * FPB;

    // ---- stage x tile: 2048 floats, one float4/thread, fully coalesced ----
    {
        const int r  = t >> 2;           // 0..127
        const int c4 = (t & 3) * 4;      // 0,4,8,12
        const float4 v = *reinterpret_cast<const float4*>(
            x + (size_t)(rbase + r) * NAM_F + f0 + c4);
        xs[r][c4+0] = v.x; xs[r][c4+1] = v.y; xs[r][c4+2] = v.z; xs[r][c4+3] = v.w;
    }

    const int lane = t & 63;
    const int w    = t >> 6;       // wave 0..7, owns rows w*16 .. w*16+15
    const int m    = lane & 15;    // A-row / B-col / D-col index
    const int hi   = lane >> 4;    // k-block select (and D row block)

    float ps0 = 0.f, ps1 = 0.f, ps2 = 0.f, ps3 = 0.f;
    float b3acc = 0.f;

    for (int p = 0; p < 8; ++p) {
        __syncthreads();   // protect previous pair's LDS reads
        // ---- stage feature pair (f0+2p, f0+2p+1) ----
        {
            const int q  = t >> 8;         // 0..1 which feature of the pair
            const int tt = t & 255;
            const int f  = f0 + 2*p + q;
            const float* W2f = W2 + (size_t)f * (NAM_H1 * NAM_H2);
            // two fully-coalesced float4 loads: flat = tt*4 + e*1024
            #pragma unroll
            for (int e = 0; e < 2; ++e) {
                const int flat = tt * 4 + e * 1024;       // element index in [0,2048)
                const int h  = flat >> 5;                 // 0..63 (same for the 4 elems)
                const int n0 = flat & 31;                 // 0,4,..,28
                const int a  = h >> 3, bb = h & 7;
                const float4 v = *reinterpret_cast<const float4*>(W2f + flat);
                w2s[q][a][n0+0][bb] = f2bf(v.x);
                w2s[q][a][n0+1][bb] = f2bf(v.y);
                w2s[q][a][n0+2][bb] = f2bf(v.z);
                w2s[q][a][n0+3][bb] = f2bf(v.w);
            }
            if (t < 128)      { int q2 = t >> 6;        w1s[q2][t & 63] = W1[(f0+2*p+q2)*NAM_H1 + (t & 63)]; }
            else if (t < 256) { int q2 = (t-128) >> 6;  b1s[q2][t & 63] = b1[(f0+2*p+q2)*NAM_H1 + (t & 63)]; }
            else if (t < 320) { int q2 = (t-256) >> 5;  b2s[q2][t & 31] = b2[(f0+2*p+q2)*NAM_H2 + (t & 31)]; }
            else if (t < 384) { int q2 = (t-320) >> 5;  w3s[q2][t & 31] = W3[(f0+2*p+q2)*NAM_H2 + (t & 31)]; }
        }
        __syncthreads();

        // ---- compute both features of the pair ----
        #pragma unroll
        for (int q = 0; q < 2; ++q) {
            const int ff = 2*p + q;
            const float xb = xs[w*16 + m][ff];

            float4_t acc0 = {0.f, 0.f, 0.f, 0.f};   // cols n = m
            float4_t acc1 = {0.f, 0.f, 0.f, 0.f};   // cols n = m+16

            #pragma unroll
            for (int s = 0; s < 2; ++s) {           // K-steps of 32 over H1=64
                // A fragment: h1[m][k], k = s*32 + hi*8 + j  (layer 1 fused)
                short8_t af;
                const int h0 = s*32 + hi*8;
                #pragma unroll
                for (int j = 0; j < 8; ++j) {
                    const float h1v = fmaxf(fmaf(xb, w1s[q][h0+j], b1s[q][h0+j]), 0.f);
                    af[j] = f2bf(h1v);
                }
                // B fragments: W2[k][n], 8 contiguous bf16 (16B aligned)
                const short8_t bf0 = *reinterpret_cast<const short8_t*>(&w2s[q][s*4+hi][m][0]);
                const short8_t bf1 = *reinterpret_cast<const short8_t*>(&w2s[q][s*4+hi][m+16][0]);
                acc0 = __builtin_amdgcn_mfma_f32_16x16x32_bf16(af, bf0, acc0, 0, 0, 0);
                acc1 = __builtin_amdgcn_mfma_f32_16x16x32_bf16(af, bf1, acc1, 0, 0, 0);
            }

            // ---- layer 3 fused: psum[r] += relu(h2+b2)*W3 over this lane's 2 cols
            const float b2a = b2s[q][m], b2b = b2s[q][m+16];
            const float w3a = w3s[q][m], w3b = w3s[q][m+16];
            ps0 += fmaxf(acc0[0]+b2a, 0.f)*w3a + fmaxf(acc1[0]+b2b, 0.f)*w3b;
            ps1 += fmaxf(acc0[1]+b2a, 0.f)*w3a + fmaxf(acc1[1]+b2b, 0.f)*w3b;
            ps2 += fmaxf(acc0[2]+b2a, 0.f)*w3a + fmaxf(acc1[2]+b2b, 0.f)*w3b;
            ps3 += fmaxf(acc0[3]+b2a, 0.f)*w3a + fmaxf(acc1[3]+b2b, 0.f)*w3b;
            b3acc += b3[f0 + ff];
        }
    }

    // ---- reduce over the 16 n-lanes (lane&15); rows (hi*4+r) stay per-lane ----
    #pragma unroll
    for (int off = 1; off < 16; off <<= 1) {
        ps0 += __shfl_xor(ps0, off);
        ps1 += __shfl_xor(ps1, off);
        ps2 += __shfl_xor(ps2, off);
        ps3 += __shfl_xor(ps3, off);
    }
    if (m == 0) {
        float4 v = make_float4(ps0 + b3acc, ps1 + b3acc, ps2 + b3acc, ps3 + b3acc);
        *reinterpret_cast<float4*>(partial + (size_t)g * NAM_B + rbase + w*16 + hi*4) = v;
    }
}

__global__ __launch_bounds__(256) void nam_phase2(
    const float* __restrict__ partial,  // [NG, B]
    const float* __restrict__ bias,     // [1]
    float* __restrict__ out)            // [2*B]: logits then probs
{
    const int b = blockIdx.x * blockDim.x + threadIdx.x;
    float s = bias[0];
    #pragma unroll
    for (int g = 0; g < NG; ++g) s += partial[(size_t)g * NAM_B + b];
    out[b] = s;
    out[NAM_B + b] = 1.0f / (1.0f + expf(-s));
}

extern "C" void kernel_launch(void* const* d_in, const int* in_sizes, int n_in,
                              void* d_out, int out_size, void* d_ws, size_t ws_size,
                              hipStream_t stream) {
    const float* x    = (const float*)d_in[0];
    const float* W1   = (const float*)d_in[1];
    const float* b1   = (const float*)d_in[2];
    const float* W2   = (const float*)d_in[3];
    const float* b2   = (const float*)d_in[4];
    const float* W3   = (const float*)d_in[5];
    const float* b3   = (const float*)d_in[6];
    const float* bias = (const float*)d_in[7];
    float* out     = (float*)d_out;
    float* partial = (float*)d_ws;   // NG*B floats = 1 MiB, fully overwritten

    nam_mfma<<<dim3(NG * NT), 512, 0, stream>>>(x, W1, b1, W2, b2, W3, b3, partial);
    nam_phase2<<<dim3(NAM_B / 256), 256, 0, stream>>>(partial, bias, out);
}

// Round 5
// 124.958 us; speedup vs baseline: 2.4018x; 1.0771x over previous
//
#include <hip/hip_runtime.h>
#include <math.h>

// NAMClassifier: B=16384 rows, F=256 independent 1->64->32->1 MLPs.
// R5 = R3/R4 resubmit (two infra timeouts): feature-per-wave, weights in
// registers, f16 packed layer-1, swapped-operand MFMA (A=W2^T, B=h1) so
// layer-3 reduce is 2 shfl_xor, b2 folded into MFMA C-operand.
// No LDS / no barriers in the hot loop.

#define NAM_B   16384
#define NAM_F   256
#define SPLITS  16
#define RPS     (NAM_B / SPLITS)   // 1024 rows per (feature, split) wave
#define TILES   (RPS / 16)         // 64
#define NGRP    8                  // partial accumulation groups

typedef __attribute__((ext_vector_type(8))) _Float16 f16x8;
typedef __attribute__((ext_vector_type(4))) _Float16 f16x4;
typedef __attribute__((ext_vector_type(2))) _Float16 f16x2;
typedef __attribute__((ext_vector_type(4))) float    f32x4;

// ---- prep 1: x[16384][256] f32 -> xT[256][16384] f16 ----
__global__ __launch_bounds__(256) void nam_xt(const float* __restrict__ x,
                                              _Float16* __restrict__ xT) {
    __shared__ float xs[64][65];
    const int t  = threadIdx.x;
    const int r0 = (blockIdx.x & 255) * 64;   // 256 row tiles
    const int c0 = (blockIdx.x >> 8) * 64;    // 4 col tiles
    const int rr = t >> 4;
    const int cc = (t & 15) * 4;
    #pragma unroll
    for (int e = 0; e < 4; ++e) {
        const float4 v = *reinterpret_cast<const float4*>(
            x + (size_t)(r0 + rr + e*16) * NAM_F + c0 + cc);
        xs[rr + e*16][cc+0] = v.x; xs[rr + e*16][cc+1] = v.y;
        xs[rr + e*16][cc+2] = v.z; xs[rr + e*16][cc+3] = v.w;
    }
    __syncthreads();
    const int wc = t >> 4;         // col within tile (base)
    const int j  = (t & 15) * 4;   // row within tile
    #pragma unroll
    for (int e = 0; e < 4; ++e) {
        const int c = wc + e*16;
        f16x4 o = {(_Float16)xs[j+0][c], (_Float16)xs[j+1][c],
                   (_Float16)xs[j+2][c], (_Float16)xs[j+3][c]};
        *reinterpret_cast<f16x4*>(xT + (size_t)(c0 + c) * NAM_B + r0 + j) = o;
    }
}

// ---- prep 2: W2[256][64][32] f32 -> f16 A-fragments [f][s][a][64 lanes][8] ----
// A-frag element j of lane L for (f,s,a): W2[f][s*32 + (L>>4)*8 + j][a*16 + (L&15)]
__global__ __launch_bounds__(256) void nam_w2p(const float* __restrict__ W2,
                                               _Float16* __restrict__ w2p) {
    const int f = blockIdx.x;
    const int t = threadIdx.x;
    const int s = t >> 7, a = (t >> 6) & 1, L = t & 63;
    const int hi = L >> 4, m = L & 15;
    const float* __restrict__ W2f = W2 + (size_t)f * (64*32);
    f16x8 o;
    #pragma unroll
    for (int j = 0; j < 8; ++j)
        o[j] = (_Float16)W2f[(s*32 + hi*8 + j)*32 + a*16 + m];
    *reinterpret_cast<f16x8*>(w2p + ((size_t)((f*2 + s)*2 + a)*64 + L) * 8) = o;
}

// ---- main: one feature per wave, 1024 rows per wave ----
__global__ __launch_bounds__(256, 4) void nam_main(
    const float* __restrict__ W1, const float* __restrict__ b1,
    const float* __restrict__ b2, const float* __restrict__ W3,
    const _Float16* __restrict__ xT, const _Float16* __restrict__ w2p,
    float* __restrict__ partial) {
    const int t    = threadIdx.x;
    const int w    = t >> 6, lane = t & 63;
    const int f     = (blockIdx.x & 63) * 4 + w;   // feature owned by this wave
    const int split = blockIdx.x >> 6;             // 0..15 row split
    const int hi = lane >> 4, m = lane & 15;

    // ---- one-time weight loads into registers ----
    const f16x8* __restrict__ wp8 = reinterpret_cast<const f16x8*>(w2p);
    const size_t fb = (size_t)f * 4 * 64;
    const f16x8 a_s0a0 = wp8[fb + 0*64 + lane];
    const f16x8 a_s0a1 = wp8[fb + 1*64 + lane];
    const f16x8 a_s1a0 = wp8[fb + 2*64 + lane];
    const f16x8 a_s1a1 = wp8[fb + 3*64 + lane];

    const float* __restrict__ w1f = W1 + f * 64;
    const float* __restrict__ b1f = b1 + f * 64;
    f16x2 w1h[8], b1h[8];        // [s*4+u] = pair (s*32+hi*8+2u, +1)
    #pragma unroll
    for (int s = 0; s < 2; ++s)
        #pragma unroll
        for (int u = 0; u < 4; ++u) {
            const int h = s*32 + hi*8 + 2*u;
            w1h[s*4+u] = (f16x2){(_Float16)w1f[h], (_Float16)w1f[h+1]};
            b1h[s*4+u] = (f16x2){(_Float16)b1f[h], (_Float16)b1f[h+1]};
        }
    const f32x4 b2v0 = *reinterpret_cast<const f32x4*>(b2 + f*32 + hi*4);
    const f32x4 b2v1 = *reinterpret_cast<const f32x4*>(b2 + f*32 + 16 + hi*4);
    const f32x4 w3v0 = *reinterpret_cast<const f32x4*>(W3 + f*32 + hi*4);
    const f32x4 w3v1 = *reinterpret_cast<const f32x4*>(W3 + f*32 + 16 + hi*4);

    const _Float16* __restrict__ xcol = xT + (size_t)f * NAM_B + split * RPS + m;
    float* __restrict__ pout = partial + (size_t)(f & 7) * NAM_B + split * RPS;

    _Float16 xc = xcol[0];
    const f16x2 hzero = {(_Float16)0.f, (_Float16)0.f};
    for (int tl = 0; tl < TILES; ++tl) {
        // prefetch next tile's x (clamped on the final iteration)
        const int pf = (tl + 1 < TILES) ? (tl + 1) * 16 : 0;
        const _Float16 xn = xcol[pf];
        const f16x2 xb = {xc, xc};
        // B-frag = h1 (layer 1, packed f16): k = s*32+hi*8+j, col = row m
        union { f16x2 h[4]; f16x8 v; } bf0, bf1;
        #pragma unroll
        for (int u = 0; u < 4; ++u) {
            bf0.h[u] = __builtin_elementwise_max(xb * w1h[u]     + b1h[u],     hzero);
            bf1.h[u] = __builtin_elementwise_max(xb * w1h[4 + u] + b1h[4 + u], hzero);
        }
        // D[h2][row], b2 folded in via C-operand
        f32x4 acc0 = __builtin_amdgcn_mfma_f32_16x16x32_f16(a_s0a0, bf0.v, b2v0, 0,0,0);
        acc0       = __builtin_amdgcn_mfma_f32_16x16x32_f16(a_s1a0, bf1.v, acc0, 0,0,0);
        f32x4 acc1 = __builtin_amdgcn_mfma_f32_16x16x32_f16(a_s0a1, bf0.v, b2v1, 0,0,0);
        acc1       = __builtin_amdgcn_mfma_f32_16x16x32_f16(a_s1a1, bf1.v, acc1, 0,0,0);
        // layer 3: this lane's 8 h2 entries of row m
        float ts = 0.f;
        #pragma unroll
        for (int r = 0; r < 4; ++r) {
            ts = fmaf(fmaxf(acc0[r], 0.f), w3v0[r], ts);
            ts = fmaf(fmaxf(acc1[r], 0.f), w3v1[r], ts);
        }
        // reduce over h2 blocks (lanes differing in bits 4,5)
        ts += __shfl_xor(ts, 16);
        ts += __shfl_xor(ts, 32);
        if (hi == 0) atomicAdd(pout + tl*16 + m, ts);
        xc = xn;
    }
}

__global__ __launch_bounds__(256) void nam_phase2(
    const float* __restrict__ partial, const float* __restrict__ b3,
    const float* __restrict__ bias, float* __restrict__ out) {
    __shared__ float red[4];
    const int t = threadIdx.x;
    float v = b3[t];                       // F = 256 = blockDim
    #pragma unroll
    for (int off = 32; off; off >>= 1) v += __shfl_xor(v, off);
    if ((t & 63) == 0) red[t >> 6] = v;
    __syncthreads();
    const float sb3 = red[0] + red[1] + red[2] + red[3];
    const int b = blockIdx.x * 256 + t;
    float s = bias[0] + sb3;
    #pragma unroll
    for (int g = 0; g < NGRP; ++g) s += partial[(size_t)g * NAM_B + b];
    out[b] = s;
    out[NAM_B + b] = 1.0f / (1.0f + expf(-s));
}

extern "C" void kernel_launch(void* const* d_in, const int* in_sizes, int n_in,
                              void* d_out, int out_size, void* d_ws, size_t ws_size,
                              hipStream_t stream) {
    const float* x    = (const float*)d_in[0];
    const float* W1   = (const float*)d_in[1];
    const float* b1   = (const float*)d_in[2];
    const float* W2   = (const float*)d_in[3];
    const float* b2   = (const float*)d_in[4];
    const float* W3   = (const float*)d_in[5];
    const float* b3   = (const float*)d_in[6];
    const float* bias = (const float*)d_in[7];
    float* out = (float*)d_out;

    // ws layout: partial (512KB) | xT f16 (8MB) | w2p f16 (1MB)  = ~9.5MB
    float*    partial = (float*)d_ws;
    _Float16* xT  = (_Float16*)((char*)d_ws + (size_t)NGRP * NAM_B * 4);
    _Float16* w2p = (_Float16*)((char*)d_ws + (size_t)NGRP * NAM_B * 4
                                            + (size_t)NAM_F * NAM_B * 2);

    hipMemsetAsync(partial, 0, (size_t)NGRP * NAM_B * 4, stream);
    nam_xt  <<<dim3(1024), 256, 0, stream>>>(x, xT);
    nam_w2p <<<dim3(NAM_F), 256, 0, stream>>>(W2, w2p);
    nam_main<<<dim3(1024), 256, 0, stream>>>(W1, b1, b2, W3, xT, w2p, partial);
    nam_phase2<<<dim3(NAM_B / 256), 256, 0, stream>>>(partial, b3, bias, out);
}